// Round 1
// baseline (948.908 us; speedup 1.0000x reference)
//
#include <hip/hip_runtime.h>
#include <hip/hip_bf16.h>
#include <math.h>

// Problem constants (from reference): B=16384, NE=32, E=128, H=256
constexpr int kB  = 16384;
constexpr int kNE = 32;
constexpr int kE  = 128;
constexpr int kH  = 256;

constexpr int MT  = 64;          // rows (batch) per block
constexpr int HC  = 64;          // h-chunk size
constexpr int NCH = kH / HC;     // 4 chunks

// LDS strides (elements). +8 keeps 16B alignment for ds_read_b128 and
// spreads banks somewhat.
constexpr int SA_S  = kE + 8;    // 136
constexpr int SW1_S = kE + 8;    // 136 (sW1 is [h][k], transposed)
constexpr int SH_S  = HC + 8;    // 72
constexpr int SW2_S = HC + 8;    // 72  (sW2 is [e][hk], transposed)

typedef __attribute__((ext_vector_type(8))) short short8;
typedef __attribute__((ext_vector_type(4))) float float4v;

__device__ __forceinline__ unsigned short f2bf(float x) {
  // round-to-nearest-even fp32 -> bf16 (no NaN handling needed here)
  unsigned int u = __float_as_uint(x);
  u += 0x7FFFu + ((u >> 16) & 1u);
  return (unsigned short)(u >> 16);
}

__global__ __launch_bounds__(256)
void distill_moe_mse(const float* __restrict__ features,
                     const float* __restrict__ target,
                     const float* __restrict__ W1,
                     const float* __restrict__ b1,
                     const float* __restrict__ W2,
                     const float* __restrict__ b2,
                     float* __restrict__ out)
{
  __shared__ __align__(16) unsigned short sA [MT * SA_S];   // [m][k]   17408 B
  __shared__ __align__(16) unsigned short sW1[HC * SW1_S];  // [h][k]   17408 B
  __shared__ __align__(16) unsigned short sH [MT * SH_S];   // [m][hk]   9216 B
  __shared__ __align__(16) unsigned short sW2[kE * SW2_S];  // [e][hk]  18432 B
  __shared__ float sRed[4];

  const int tid  = threadIdx.x;
  const int lane = tid & 63;
  const int w    = tid >> 6;     // wave 0..3
  const int q    = lane >> 4;    // quad 0..3
  const int col  = lane & 15;

  const int n  = blockIdx.y;           // expert
  const int b0 = blockIdx.x * MT;      // batch-row base

  // GEMM2 wave tiling: wave -> 32x64 quadrant of the 64x128 pred tile
  const int wr = w >> 1;   // row half  (rows 32*wr .. +32)
  const int wc = w & 1;    // col half  (cols 64*wc .. +64)

  const float* W1n = W1 + (size_t)n * kE * kH;
  const float* W2n = W2 + (size_t)n * kH * kE;

  float4v accP[2][4];
#pragma unroll
  for (int i = 0; i < 2; ++i)
#pragma unroll
    for (int j = 0; j < 4; ++j)
      accP[i][j] = (float4v){0.f, 0.f, 0.f, 0.f};

  // ---- stage A tile: sA[m][k] = bf16(features[b0+m][n][k]) ----
  {
    const float* src = features + ((size_t)b0 * kNE + (size_t)n) * kE;
#pragma unroll
    for (int i = 0; i < 8; ++i) {
      int idx = i * 256 + tid;          // 0..2047 (float4 index)
      int m   = idx >> 5;               // 0..63
      int k   = (idx & 31) << 2;        // 0..124 step 4
      float4v f = *(const float4v*)(src + (size_t)m * (kNE * kE) + k);
      unsigned short* d = &sA[m * SA_S + k];
      d[0] = f2bf(f.x); d[1] = f2bf(f.y); d[2] = f2bf(f.z); d[3] = f2bf(f.w);
    }
  }
  // first __syncthreads() happens at top of chunk loop

  for (int c = 0; c < NCH; ++c) {
    const int hc0 = c * HC;
    __syncthreads();  // prev-chunk GEMM2 readers done / A-stage visible

    // ---- stage W1 chunk transposed: sW1[h][k] = bf16(W1n[k][hc0+h]) ----
#pragma unroll
    for (int i = 0; i < 8; ++i) {
      int idx = i * 256 + tid;       // 0..2047
      int k   = idx >> 4;            // 0..127
      int h   = (idx & 15) << 2;     // 0..60 step 4
      float4v f = *(const float4v*)(W1n + (size_t)k * kH + hc0 + h);
      sW1[(h + 0) * SW1_S + k] = f2bf(f.x);
      sW1[(h + 1) * SW1_S + k] = f2bf(f.y);
      sW1[(h + 2) * SW1_S + k] = f2bf(f.z);
      sW1[(h + 3) * SW1_S + k] = f2bf(f.w);
    }
    // ---- stage W2 chunk transposed: sW2[e][hk] = bf16(W2n[hc0+hk][e]) ----
#pragma unroll
    for (int i = 0; i < 8; ++i) {
      int idx = i * 256 + tid;       // 0..2047
      int hk  = idx >> 5;            // 0..63
      int e   = (idx & 31) << 2;     // 0..124 step 4
      float4v f = *(const float4v*)(W2n + (size_t)(hc0 + hk) * kE + e);
      sW2[(e + 0) * SW2_S + hk] = f2bf(f.x);
      sW2[(e + 1) * SW2_S + hk] = f2bf(f.y);
      sW2[(e + 2) * SW2_S + hk] = f2bf(f.z);
      sW2[(e + 3) * SW2_S + hk] = f2bf(f.w);
    }
    __syncthreads();

    // ---- GEMM1: wave w computes rows 16w..16w+15 x hcols [hc0, hc0+64) ----
    {
      float4v acc[4];
#pragma unroll
      for (int t = 0; t < 4; ++t) acc[t] = (float4v){0.f, 0.f, 0.f, 0.f};
      const int m0 = 16 * w;
#pragma unroll
      for (int kt = 0; kt < 4; ++kt) {
        const int k0 = 32 * kt;
        short8 a = *(const short8*)&sA[(m0 + col) * SA_S + k0 + q * 8];
#pragma unroll
        for (int t = 0; t < 4; ++t) {
          short8 b = *(const short8*)&sW1[(16 * t + col) * SW1_S + k0 + q * 8];
          acc[t] = __builtin_amdgcn_mfma_f32_16x16x32_bf16(a, b, acc[t], 0, 0, 0);
        }
      }
      // bias + exact-erf gelu, write to sH[m][hk] (C-layout -> A-layout via LDS)
#pragma unroll
      for (int t = 0; t < 4; ++t) {
        float bias = b1[n * kH + hc0 + 16 * t + col];
#pragma unroll
        for (int r = 0; r < 4; ++r) {
          float x = acc[t][r] + bias;
          float g = 0.5f * x * (1.0f + erff(x * 0.70710678118654752f));
          sH[(m0 + q * 4 + r) * SH_S + 16 * t + col] = f2bf(g);
        }
      }
    }
    __syncthreads();

    // ---- GEMM2 partial: rows 32*wr+[0,32), cols 64*wc+[0,64), k = chunk ----
#pragma unroll
    for (int kt = 0; kt < 2; ++kt) {
      const int k0 = 32 * kt;
      short8 a[2];
#pragma unroll
      for (int i = 0; i < 2; ++i)
        a[i] = *(const short8*)&sH[(32 * wr + 16 * i + col) * SH_S + k0 + q * 8];
#pragma unroll
      for (int j = 0; j < 4; ++j) {
        short8 bf = *(const short8*)&sW2[(64 * wc + 16 * j + col) * SW2_S + k0 + q * 8];
#pragma unroll
        for (int i = 0; i < 2; ++i)
          accP[i][j] = __builtin_amdgcn_mfma_f32_16x16x32_bf16(a[i], bf, accP[i][j], 0, 0, 0);
      }
    }
  }

  // ---- epilogue: +b2, diff vs target, square, reduce, atomicAdd ----
  {
    float local = 0.f;
#pragma unroll
    for (int j = 0; j < 4; ++j) {
      int e = 64 * wc + 16 * j + col;
      float bias = b2[n * kE + e];
#pragma unroll
      for (int i = 0; i < 2; ++i) {
#pragma unroll
        for (int r = 0; r < 4; ++r) {
          int m = 32 * wr + 16 * i + q * 4 + r;
          float pred = accP[i][j][r] + bias;
          float tgt = target[((size_t)(b0 + m) * kNE + n) * kE + e];
          float d = pred - tgt;
          local += d * d;
        }
      }
    }
#pragma unroll
    for (int off = 32; off > 0; off >>= 1)
      local += __shfl_down(local, off, 64);
    if (lane == 0) sRed[w] = local;
    __syncthreads();
    if (tid == 0) {
      float s = sRed[0] + sRed[1] + sRed[2] + sRed[3];
      atomicAdd(out, s * (1.0f / ((float)kB * (float)kNE * (float)kE)));
    }
  }
}

extern "C" void kernel_launch(void* const* d_in, const int* in_sizes, int n_in,
                              void* d_out, int out_size, void* d_ws, size_t ws_size,
                              hipStream_t stream) {
  const float* features = (const float*)d_in[0];
  const float* target   = (const float*)d_in[1];
  const float* W1       = (const float*)d_in[2];
  const float* b1       = (const float*)d_in[3];
  const float* W2       = (const float*)d_in[4];
  const float* b2       = (const float*)d_in[5];
  float* out = (float*)d_out;

  // d_out is poisoned to 0xAA before every timed launch; we accumulate into it.
  hipMemsetAsync(out, 0, sizeof(float), stream);

  dim3 grid(kB / MT, kNE);
  dim3 block(256);
  distill_moe_mse<<<grid, block, 0, stream>>>(features, target, W1, b1, W2, b2, out);
}

// Round 2
// 633.212 us; speedup vs baseline: 1.4986x; 1.4986x over previous
//
#include <hip/hip_runtime.h>
#include <hip/hip_bf16.h>
#include <math.h>

// Problem constants: B=16384, NE=32, E=128, H=256
constexpr int kB  = 16384;
constexpr int kNE = 32;
constexpr int kE  = 128;
constexpr int kH  = 256;

constexpr int MT  = 64;          // rows (batch) per block
constexpr int HC  = 64;          // h-chunk size
constexpr int NCH = kH / HC;     // 4 chunks

// LDS strides (elements). +8 keeps 16B alignment for ds_read_b128/ds_write_b128
// (row stride 272B / 144B, both %16==0) and offsets rows by 4 banks.
constexpr int SA_S  = kE + 8;    // 136
constexpr int SW1_S = kE + 8;    // 136 (sW1 is [h][k])
constexpr int SH_S  = HC + 8;    // 72
constexpr int SW2_S = HC + 8;    // 72  (sW2 is [e][hk])

typedef __attribute__((ext_vector_type(8))) short short8;
typedef __attribute__((ext_vector_type(4))) float float4v;

__device__ __forceinline__ unsigned short f2bf(float x) {
  unsigned int u = __float_as_uint(x);
  u += 0x7FFFu + ((u >> 16) & 1u);
  return (unsigned short)(u >> 16);
}

// tanh-form GELU: x * sigmoid(2*0.797885*(x+0.044715x^3)), sigmoid via exp2.
// |gelu_tanh - gelu_erf| < ~1e-3; loss perturbation << 2.9e-2 threshold.
__device__ __forceinline__ float gelu_f(float x) {
  float x2 = x * x;
  // w = -2*ln2^-1... : w = x*(c1 + c2*x2), exp(-2u) = exp2(w)
  float w = x * fmaf(x2, -0.10294428f, -2.30220795f);
  float z = __builtin_amdgcn_exp2f(w);
  return x * __builtin_amdgcn_rcpf(1.0f + z);
}

// ---------------- prep: transpose + fp32->bf16 convert weights ----------------
// z < kNE : expert z, W1 [E=128 rows(k)][H=256 cols(h)] -> W1T [h][k]
// z >= kNE: expert z-kNE, W2 [H=256 rows(h)][E=128 cols(e)] -> W2T [e][h]
__global__ __launch_bounds__(256)
void prep_weights(const float* __restrict__ W1, const float* __restrict__ W2,
                  unsigned short* __restrict__ W1T, unsigned short* __restrict__ W2T)
{
  __shared__ unsigned short tile[32][33];
  const int x = threadIdx.x;       // 0..31
  const int y = threadIdx.y;       // 0..7
  int z = blockIdx.z;
  const float* src;
  unsigned short* dst;
  int M, N;                        // src is M rows x N cols
  if (z < kNE) {
    M = kE; N = kH;
    src = W1 + (size_t)z * kE * kH;
    dst = W1T + (size_t)z * kH * kE;
  } else {
    z -= kNE;
    M = kH; N = kE;
    src = W2 + (size_t)z * kH * kE;
    dst = W2T + (size_t)z * kE * kH;
  }
  const int tn = blockIdx.x;       // tile col (over N)
  const int tm = blockIdx.y;       // tile row (over M)
  if (tn * 32 >= N || tm * 32 >= M) return;

#pragma unroll
  for (int r = 0; r < 4; ++r) {
    int row = tm * 32 + y + r * 8;
    int col = tn * 32 + x;
    tile[y + r * 8][x] = f2bf(src[(size_t)row * N + col]);
  }
  __syncthreads();
#pragma unroll
  for (int r = 0; r < 4; ++r) {
    int row = tn * 32 + y + r * 8;   // output row (over N)
    int col = tm * 32 + x;           // output col (over M)
    dst[(size_t)row * M + col] = tile[x][y + r * 8];
  }
}

// ---------------- main kernel ----------------
__global__ __launch_bounds__(256)
void distill_moe_mse(const float* __restrict__ features,
                     const float* __restrict__ target,
                     const unsigned short* __restrict__ W1T,  // [NE][H][E] bf16
                     const float* __restrict__ b1,
                     const unsigned short* __restrict__ W2T,  // [NE][E][H] bf16
                     const float* __restrict__ b2,
                     float* __restrict__ out)
{
  __shared__ __align__(16) unsigned short sA [MT * SA_S];   // [m][k]
  __shared__ __align__(16) unsigned short sW1[HC * SW1_S];  // [h][k]
  __shared__ __align__(16) unsigned short sH [MT * SH_S];   // [m][hk]
  __shared__ __align__(16) unsigned short sW2[kE * SW2_S];  // [e][hk]
  __shared__ float sRed[4];

  const int tid  = threadIdx.x;
  const int lane = tid & 63;
  const int w    = tid >> 6;     // wave 0..3
  const int q    = lane >> 4;    // quad 0..3
  const int col  = lane & 15;

  const int n  = blockIdx.y;           // expert
  const int b0 = blockIdx.x * MT;      // batch-row base

  const int wr = w >> 1;   // GEMM2 row half
  const int wc = w & 1;    // GEMM2 col half

  const unsigned short* W1n = W1T + (size_t)n * kH * kE;
  const unsigned short* W2n = W2T + (size_t)n * kE * kH;

  float4v accP[2][4];
#pragma unroll
  for (int i = 0; i < 2; ++i)
#pragma unroll
    for (int j = 0; j < 4; ++j)
      accP[i][j] = (float4v){0.f, 0.f, 0.f, 0.f};

  // ---- stage A tile: sA[m][k] = bf16(features[b0+m][n][k]), packed b128 ----
  {
    const float* src = features + ((size_t)b0 * kNE + (size_t)n) * kE;
#pragma unroll
    for (int i = 0; i < 4; ++i) {
      int idx = i * 256 + tid;          // 0..1023 (8-elt chunk index)
      int m   = idx >> 4;               // 0..63
      int k   = (idx & 15) << 3;        // 0..120 step 8
      const float* p = src + (size_t)m * (kNE * kE) + k;
      float4v f0 = *(const float4v*)(p);
      float4v f1 = *(const float4v*)(p + 4);
      short8 v;
      v[0] = (short)f2bf(f0.x); v[1] = (short)f2bf(f0.y);
      v[2] = (short)f2bf(f0.z); v[3] = (short)f2bf(f0.w);
      v[4] = (short)f2bf(f1.x); v[5] = (short)f2bf(f1.y);
      v[6] = (short)f2bf(f1.z); v[7] = (short)f2bf(f1.w);
      *(short8*)&sA[m * SA_S + k] = v;
    }
  }

  for (int c = 0; c < NCH; ++c) {
    const int hc0 = c * HC;
    __syncthreads();  // prev-chunk GEMM2 readers done / A-stage visible

    // ---- stage W1 chunk: sW1[h][k] <- W1T[(hc0+h)*128 + k], b128 copy ----
#pragma unroll
    for (int i = 0; i < 4; ++i) {
      int idx = i * 256 + tid;       // 0..1023
      int h   = idx >> 4;            // 0..63
      int kb  = idx & 15;            // 16B block
      short8 v = *(const short8*)(W1n + (size_t)(hc0 + h) * kE + kb * 8);
      *(short8*)&sW1[h * SW1_S + kb * 8] = v;
    }
    // ---- stage W2 chunk: sW2[e][hk] <- W2T[e*256 + hc0 + hk], b128 copy ----
#pragma unroll
    for (int i = 0; i < 4; ++i) {
      int idx = i * 256 + tid;       // 0..1023
      int e   = idx >> 3;            // 0..127
      int hb  = idx & 7;             // 16B block
      short8 v = *(const short8*)(W2n + (size_t)e * kH + hc0 + hb * 8);
      *(short8*)&sW2[e * SW2_S + hb * 8] = v;
    }
    __syncthreads();

    // ---- GEMM1: wave w -> rows 16w..16w+15 x hcols [hc0, hc0+64) ----
    {
      float4v acc[4];
#pragma unroll
      for (int t = 0; t < 4; ++t) acc[t] = (float4v){0.f, 0.f, 0.f, 0.f};
      const int m0 = 16 * w;
#pragma unroll
      for (int kt = 0; kt < 4; ++kt) {
        const int k0 = 32 * kt;
        short8 a = *(const short8*)&sA[(m0 + col) * SA_S + k0 + q * 8];
#pragma unroll
        for (int t = 0; t < 4; ++t) {
          short8 b = *(const short8*)&sW1[(16 * t + col) * SW1_S + k0 + q * 8];
          acc[t] = __builtin_amdgcn_mfma_f32_16x16x32_bf16(a, b, acc[t], 0, 0, 0);
        }
      }
      // bias + gelu, C-layout -> A-layout via LDS
#pragma unroll
      for (int t = 0; t < 4; ++t) {
        float bias = b1[n * kH + hc0 + 16 * t + col];
#pragma unroll
        for (int r = 0; r < 4; ++r) {
          float x = acc[t][r] + bias;
          sH[(m0 + q * 4 + r) * SH_S + 16 * t + col] = f2bf(gelu_f(x));
        }
      }
    }
    __syncthreads();

    // ---- GEMM2 partial: rows 32*wr+[0,32), cols 64*wc+[0,64) ----
#pragma unroll
    for (int kt = 0; kt < 2; ++kt) {
      const int k0 = 32 * kt;
      short8 a[2];
#pragma unroll
      for (int i = 0; i < 2; ++i)
        a[i] = *(const short8*)&sH[(32 * wr + 16 * i + col) * SH_S + k0 + q * 8];
#pragma unroll
      for (int j = 0; j < 4; ++j) {
        short8 bf = *(const short8*)&sW2[(64 * wc + 16 * j + col) * SW2_S + k0 + q * 8];
#pragma unroll
        for (int i = 0; i < 2; ++i)
          accP[i][j] = __builtin_amdgcn_mfma_f32_16x16x32_bf16(a[i], bf, accP[i][j], 0, 0, 0);
      }
    }
  }

  // ---- epilogue: +b2, diff vs target, square, reduce, atomicAdd ----
  {
    float local = 0.f;
#pragma unroll
    for (int j = 0; j < 4; ++j) {
      int e = 64 * wc + 16 * j + col;
      float bias = b2[n * kE + e];
#pragma unroll
      for (int i = 0; i < 2; ++i) {
#pragma unroll
        for (int r = 0; r < 4; ++r) {
          int m = 32 * wr + 16 * i + q * 4 + r;
          float pred = accP[i][j][r] + bias;
          float tgt = target[((size_t)(b0 + m) * kNE + n) * kE + e];
          float d = pred - tgt;
          local += d * d;
        }
      }
    }
#pragma unroll
    for (int off = 32; off > 0; off >>= 1)
      local += __shfl_down(local, off, 64);
    if (lane == 0) sRed[w] = local;
    __syncthreads();
    if (tid == 0) {
      float s = sRed[0] + sRed[1] + sRed[2] + sRed[3];
      atomicAdd(out, s * (1.0f / ((float)kB * (float)kNE * (float)kE)));
    }
  }
}

extern "C" void kernel_launch(void* const* d_in, const int* in_sizes, int n_in,
                              void* d_out, int out_size, void* d_ws, size_t ws_size,
                              hipStream_t stream) {
  const float* features = (const float*)d_in[0];
  const float* target   = (const float*)d_in[1];
  const float* W1       = (const float*)d_in[2];
  const float* b1       = (const float*)d_in[3];
  const float* W2       = (const float*)d_in[4];
  const float* b2       = (const float*)d_in[5];
  float* out = (float*)d_out;

  unsigned short* W1T = (unsigned short*)d_ws;                        // 2 MB
  unsigned short* W2T = W1T + (size_t)kNE * kH * kE;                  // 2 MB

  hipMemsetAsync(out, 0, sizeof(float), stream);

  {
    dim3 grid(8, 8, 2 * kNE);
    dim3 block(32, 8);
    prep_weights<<<grid, block, 0, stream>>>(W1, W2, W1T, W2T);
  }
  {
    dim3 grid(kB / MT, kNE);
    dim3 block(256);
    distill_moe_mse<<<grid, block, 0, stream>>>(features, target, W1T, b1, W2T, b2, out);
  }
}